// Round 4
// baseline (323.373 us; speedup 1.0000x reference)
//
#include <hip/hip_runtime.h>

// Guided filter r=3 (7x7 box, zero-pad /49), fused streaming kernel. R10.
// R8/R9 post-mortem: LDS-pipe-bound (~106us ideal demand, x1.4 measured);
// occupancy is NOT the limiter (R9: 10 blocks/CU, same 153us). R10 cuts
// LDS cycles 1.6x: 2 columns/thread, so one 8-element tap read serves two
// 7-wide windows (4 reads/col vs 7). PARITY-SPLIT LDS layout (even/odd
// element arrays; thread t writes both at idx t+2, reads even t+1..t+4,
// odd t..t+3) keeps every ds op lane-dense 16B-stride (naive C=2 would be
// stride-32B = 2x bank cycles). Register rebalance so C=2 fits: raw ring
// dropped (leaving row re-read from global, L2-resident; FETCH counts HBM
// only), Io via 1-row-lead reload. Only ab ring (96f) + colsums persist.
// Single-wave blocks, NO __syncthreads in the row loop: same-wave LDS RAW
// is ordered by in-order issue + may-alias waitcnts (write idx t+2 vs
// read idx t+d alias at d=2); asm memory clobbers pin phase order.
//
// Thread = 2 adjacent image columns. Block = 64 threads = 128 input cols
// (116 output). Block sweeps 76 rows (r=0..75): entering raw row y=Yb+r,
// ab row yc=y-3, output row o=y-6. Vertical box sums: rolling register
// colsums; leaving raw row reloaded from global (7-row lag, L2 hit),
// leaving ab from depth-8 register ring (slot = r&7, static via unroll).
// Horizontal 7-taps: parity-split LDS colsum rows, 2 slots (r&1).
// LDS = 15,232 B. Grid 9x16x8 = 1152 blocks (4.5/CU).

typedef float v4 __attribute__((ext_vector_type(4)));
typedef float v2 __attribute__((ext_vector_type(2)));

#define TPB   64
#define OUTW  116
#define SEGH  64
#define HW    1024
#define NIDX  68           // 64 data + guards per parity array
#define EPSF  1e-6f
#define INV49 (1.0f/49.0f)

struct St {
    v4 s14[2], s58[2];         // stage-1 colsums per col: (I,II,p0,p1),(p2,q0,q1,q2)
    v4 t64[2]; v2 t62[2];      // stage-2 colsums per col: (a0,b0,a1,b1),(a2,b2)
    v4 rab4[8][2]; v2 rab2[8][2]; // ab ring, slot = r&7 (static via unroll)
    v4 ent[2][2];              // entering raw rows, ping-pong [r&1][col]
    v4 lv[2], lvN[2];          // leaving raw row (reloaded, 1-row lead)
    v2 Io, IoN;                // I at output row (1-row lead)
};

template<int U>
__device__ __forceinline__ void rowStep(
    St& S, const int r, const int Yb, const int t, const int xc2,
    const bool ok0, const bool ok1, const bool sok, const int x0,
    const float* __restrict__ Ip, const float* __restrict__ P0,
    const float* __restrict__ P1, const float* __restrict__ P2,
    float* __restrict__ Q0, float* __restrict__ Q1, float* __restrict__ Q2,
    v4 (* __restrict__ c8)[2][2][NIDX],
    v4 (* __restrict__ c6A)[2][NIDX],
    v2 (* __restrict__ c6B)[2][NIDX])
{
    constexpr int SU = U & 1;        // LDS slot
    constexpr int WS = U;            // ab-ring write slot (r&7 == U)
    constexpr int LS = (U + 1) & 7;  // ab-ring leaving slot (row r-7)

    // ---- A: stage-1 vertical colsum update (enter y, leave y-7) -> cs8
    #pragma unroll
    for (int c = 0; c < 2; ++c) {
        const v4 cE = S.ent[SU][c];
        const v4 L  = S.lv[c];
        v4 d14, d58;
        d14.x = cE.x - L.x;
        d14.y = cE.x*cE.x - L.x*L.x;
        d14.z = cE.y - L.y;
        d14.w = cE.z - L.z;
        d58.x = cE.w - L.w;
        d58.y = cE.x*cE.y - L.x*L.y;
        d58.z = cE.x*cE.z - L.x*L.z;
        d58.w = cE.x*cE.w - L.x*L.w;
        S.s14[c] += d14;
        S.s58[c] += d58;
        c8[SU][c][0][t+2] = S.s14[c];   // parity c, dense 16B stride
        c8[SU][c][1][t+2] = S.s58[c];
    }
    asm volatile("" ::: "memory");

    // ---- B: stage-1 horizontal 7-tap (parity-split sliding) -> ab ->
    //         ab-ring / stage-2 colsum update -> cs6
    {
        const v4 e14_1 = c8[SU][0][0][t+1], e14_2 = c8[SU][0][0][t+2],
                 e14_3 = c8[SU][0][0][t+3], e14_4 = c8[SU][0][0][t+4];
        const v4 o14_0 = c8[SU][1][0][t+0], o14_1 = c8[SU][1][0][t+1],
                 o14_2 = c8[SU][1][0][t+2], o14_3 = c8[SU][1][0][t+3];
        const v4 w14 = (e14_1 + e14_2 + e14_3) + (o14_1 + o14_2 + o14_3);
        v4 W14[2]; W14[0] = w14 + o14_0; W14[1] = w14 + e14_4;

        const v4 e58_1 = c8[SU][0][1][t+1], e58_2 = c8[SU][0][1][t+2],
                 e58_3 = c8[SU][0][1][t+3], e58_4 = c8[SU][0][1][t+4];
        const v4 o58_0 = c8[SU][1][1][t+0], o58_1 = c8[SU][1][1][t+1],
                 o58_2 = c8[SU][1][1][t+2], o58_3 = c8[SU][1][1][t+3];
        const v4 w58 = (e58_1 + e58_2 + e58_3) + (o58_1 + o58_2 + o58_3);
        v4 W58[2]; W58[0] = w58 + o58_0; W58[1] = w58 + e58_4;

        const int  yc   = Yb + r - 3;
        const bool ycok = (unsigned)yc < HW;
        const bool okc[2] = {ok0, ok1};
        #pragma unroll
        for (int c = 0; c < 2; ++c) {
            const v4 A = W14[c], B = W58[c];
            const float mi  = A.x * INV49;
            const float mii = A.y * INV49;
            const float rv  = __builtin_amdgcn_rcpf(mii - mi*mi + EPSF);
            const bool abok = ycok && okc[c];
            const float mp0 = A.z*INV49, mp1 = A.w*INV49, mp2 = B.x*INV49;
            const float a0 = (B.y*INV49 - mi*mp0)*rv;
            const float a1 = (B.z*INV49 - mi*mp1)*rv;
            const float a2 = (B.w*INV49 - mi*mp2)*rv;
            const float b0 = fmaf(-a0, mi, mp0);
            const float b1 = fmaf(-a1, mi, mp1);
            const float b2 = fmaf(-a2, mi, mp2);
            v4 ab4; ab4.x = abok?a0:0.f; ab4.y = abok?b0:0.f;
                    ab4.z = abok?a1:0.f; ab4.w = abok?b1:0.f;
            v2 ab2; ab2.x = abok?a2:0.f; ab2.y = abok?b2:0.f;
            S.t64[c] += ab4 - S.rab4[LS][c];  S.rab4[WS][c] = ab4;
            S.t62[c] += ab2 - S.rab2[LS][c];  S.rab2[WS][c] = ab2;
            c6A[SU][c][t+2] = S.t64[c];
            c6B[SU][c][t+2] = S.t62[c];
        }
    }
    asm volatile("" ::: "memory");

    // ---- C: prefetch (entering row r+2 from HBM; leaving row & Io for
    //         row r+1 from L2). Uniform-y branches; per-lane x predicates.
    {
        const int yE = Yb + r + 2;
        if ((unsigned)yE < HW) {
            const size_t ro = (size_t)yE * HW + xc2;
            const v2 vI = *(const v2*)(Ip + ro);
            const v2 va = *(const v2*)(P0 + ro);
            const v2 vb = *(const v2*)(P1 + ro);
            const v2 vc = *(const v2*)(P2 + ro);
            v4 E0, E1;
            E0.x = ok0?vI.x:0.f; E0.y = ok0?va.x:0.f; E0.z = ok0?vb.x:0.f; E0.w = ok0?vc.x:0.f;
            E1.x = ok1?vI.y:0.f; E1.y = ok1?va.y:0.f; E1.z = ok1?vb.y:0.f; E1.w = ok1?vc.y:0.f;
            S.ent[SU][0] = E0; S.ent[SU][1] = E1;
        } else {
            const v4 z = {0.f,0.f,0.f,0.f};
            S.ent[SU][0] = z; S.ent[SU][1] = z;
        }
        const int yL = Yb + r - 6;         // leaving row for row r+1
        if (r >= 6 && (unsigned)yL < HW) { // r>=6: rows r<7 never entered
            const size_t ro = (size_t)yL * HW + xc2;
            const v2 vI = *(const v2*)(Ip + ro);
            const v2 va = *(const v2*)(P0 + ro);
            const v2 vb = *(const v2*)(P1 + ro);
            const v2 vc = *(const v2*)(P2 + ro);
            v4 L0, L1;
            L0.x = ok0?vI.x:0.f; L0.y = ok0?va.x:0.f; L0.z = ok0?vb.x:0.f; L0.w = ok0?vc.x:0.f;
            L1.x = ok1?vI.y:0.f; L1.y = ok1?va.y:0.f; L1.z = ok1?vb.y:0.f; L1.w = ok1?vc.y:0.f;
            S.lvN[0] = L0; S.lvN[1] = L1;
        } else {
            const v4 z = {0.f,0.f,0.f,0.f};
            S.lvN[0] = z; S.lvN[1] = z;
        }
        const int yO = Yb + r - 5;         // output row of row r+1
        if ((unsigned)yO < HW) {
            const size_t ro = (size_t)yO * HW + xc2;
            const v2 vio = *(const v2*)(Ip + ro);
            S.IoN.x = ok0?vio.x:0.f; S.IoN.y = ok1?vio.y:0.f;
        } else { S.IoN.x = 0.f; S.IoN.y = 0.f; }
    }

    // ---- D: stage-2 horizontal 7-tap -> output row o = y-6
    if ((unsigned)(r - 12) <= 63u) {
        const v4 eA1 = c6A[SU][0][t+1], eA2 = c6A[SU][0][t+2],
                 eA3 = c6A[SU][0][t+3], eA4 = c6A[SU][0][t+4];
        const v4 oA0 = c6A[SU][1][t+0], oA1 = c6A[SU][1][t+1],
                 oA2 = c6A[SU][1][t+2], oA3 = c6A[SU][1][t+3];
        const v2 eB1 = c6B[SU][0][t+1], eB2 = c6B[SU][0][t+2],
                 eB3 = c6B[SU][0][t+3], eB4 = c6B[SU][0][t+4];
        const v2 oB0 = c6B[SU][1][t+0], oB1 = c6B[SU][1][t+1],
                 oB2 = c6B[SU][1][t+2], oB3 = c6B[SU][1][t+3];
        const v4 wA = (eA1+eA2+eA3) + (oA1+oA2+oA3);
        const v2 wB = (eB1+eB2+eB3) + (oB1+oB2+oB3);
        const v4 A0 = wA + oA0, A1 = wA + eA4;
        const v2 B0 = wB + oB0, B1 = wB + eB4;
        if (sok) {
            const int o = Yb + r - 6;
            const size_t ob = (size_t)o * HW + x0;
            v2 q;
            q.x = fminf(fmaxf(fmaf(A0.x*INV49, S.Io.x, A0.y*INV49), 0.f), 1.f);
            q.y = fminf(fmaxf(fmaf(A1.x*INV49, S.Io.y, A1.y*INV49), 0.f), 1.f);
            *(v2*)(Q0 + ob) = q;
            q.x = fminf(fmaxf(fmaf(A0.z*INV49, S.Io.x, A0.w*INV49), 0.f), 1.f);
            q.y = fminf(fmaxf(fmaf(A1.z*INV49, S.Io.y, A1.w*INV49), 0.f), 1.f);
            *(v2*)(Q1 + ob) = q;
            q.x = fminf(fmaxf(fmaf(B0.x*INV49, S.Io.x, B0.y*INV49), 0.f), 1.f);
            q.y = fminf(fmaxf(fmaf(B1.x*INV49, S.Io.y, B1.y*INV49), 0.f), 1.f);
            *(v2*)(Q2 + ob) = q;
        }
    }
    S.lv[0] = S.lvN[0]; S.lv[1] = S.lvN[1];
    S.Io = S.IoN;
}

__global__ __launch_bounds__(TPB, 2) void gf_kernel(
    const float* __restrict__ I, const float* __restrict__ P,
    float* __restrict__ Q)
{
    // parity-split colsum rows: [slot][parity][part][idx]
    __shared__ v4 c8[2][2][2][NIDX];   // 8704 B (stage-1, 32 B/element)
    __shared__ v4 c6A[2][2][NIDX];     // 4352 B (stage-2 a0,b0,a1,b1)
    __shared__ v2 c6B[2][2][NIDX];     // 2176 B (stage-2 a2,b2)  -> 15232 B

    const int s   = blockIdx.x;      // x-stripe (9)
    const int seg = blockIdx.y;      // y-segment (16)
    const int b   = blockIdx.z;      // batch (8)
    const int t   = threadIdx.x;

    const int Yb = seg*SEGH - 6;
    const int x0 = s*OUTW - 6 + 2*t;           // even always
    const int x1 = x0 + 1;
    const bool ok0 = (unsigned)x0 < HW;
    const bool ok1 = (unsigned)x1 < HW;
    const int  xc2 = min(max(x0, 0), HW-2);    // valid base for v2 loads
    const bool sok = (t >= 3) && (t <= 60) && ok0 && ok1;

    const float* Ip = I + (size_t)b*HW*HW;
    const float* P0 = P + ((size_t)b*3 + 0)*HW*HW;
    const float* P1 = P + ((size_t)b*3 + 1)*HW*HW;
    const float* P2 = P + ((size_t)b*3 + 2)*HW*HW;
    float* Q0 = Q + ((size_t)b*3 + 0)*HW*HW;
    float* Q1 = Q + ((size_t)b*3 + 1)*HW*HW;
    float* Q2 = Q + ((size_t)b*3 + 2)*HW*HW;

    // zero-init LDS (guard cells must read as 0; interiors rewritten)
    {
        const v4 z4 = {0.f,0.f,0.f,0.f};
        const v2 z2 = {0.f,0.f};
        v4* a = (v4*)c8;
        #pragma unroll 2
        for (int i = t; i < 2*2*2*NIDX; i += TPB) a[i] = z4;
        v4* bb = (v4*)c6A;
        for (int i = t; i < 2*2*NIDX; i += TPB) bb[i] = z4;
        v2* cc = (v2*)c6B;
        for (int i = t; i < 2*2*NIDX; i += TPB) cc[i] = z2;
    }

    St S;
    {
        const v4 z4 = {0.f,0.f,0.f,0.f};
        const v2 z2 = {0.f,0.f};
        #pragma unroll
        for (int c = 0; c < 2; ++c) {
            S.s14[c] = z4; S.s58[c] = z4; S.t64[c] = z4; S.t62[c] = z2;
            S.lv[c] = z4; S.lvN[c] = z4;
            #pragma unroll
            for (int i = 0; i < 8; ++i) { S.rab4[i][c] = z4; S.rab2[i][c] = z2; }
        }
        S.Io = z2; S.IoN = z2;
        // prologue: entering rows 0,1
        #pragma unroll
        for (int pr = 0; pr < 2; ++pr) {
            const int yE = Yb + pr;
            if ((unsigned)yE < HW) {
                const size_t ro = (size_t)yE * HW + xc2;
                const v2 vI = *(const v2*)(Ip + ro);
                const v2 va = *(const v2*)(P0 + ro);
                const v2 vb = *(const v2*)(P1 + ro);
                const v2 vc = *(const v2*)(P2 + ro);
                v4 E0, E1;
                E0.x = ok0?vI.x:0.f; E0.y = ok0?va.x:0.f; E0.z = ok0?vb.x:0.f; E0.w = ok0?vc.x:0.f;
                E1.x = ok1?vI.y:0.f; E1.y = ok1?va.y:0.f; E1.z = ok1?vb.y:0.f; E1.w = ok1?vc.y:0.f;
                S.ent[pr][0] = E0; S.ent[pr][1] = E1;
            } else {
                S.ent[pr][0] = z4; S.ent[pr][1] = z4;
            }
        }
    }
    __syncthreads();   // LDS zero-init visible (single wave: cheap)

    // 76 rows: r = 0..75 (ring slot r&7 == U by construction)
    for (int m = 0; m < 9; ++m) {
        const int r0 = m*8;
        rowStep<0>(S, r0+0, Yb, t, xc2, ok0, ok1, sok, x0, Ip,P0,P1,P2, Q0,Q1,Q2, c8,c6A,c6B);
        rowStep<1>(S, r0+1, Yb, t, xc2, ok0, ok1, sok, x0, Ip,P0,P1,P2, Q0,Q1,Q2, c8,c6A,c6B);
        rowStep<2>(S, r0+2, Yb, t, xc2, ok0, ok1, sok, x0, Ip,P0,P1,P2, Q0,Q1,Q2, c8,c6A,c6B);
        rowStep<3>(S, r0+3, Yb, t, xc2, ok0, ok1, sok, x0, Ip,P0,P1,P2, Q0,Q1,Q2, c8,c6A,c6B);
        rowStep<4>(S, r0+4, Yb, t, xc2, ok0, ok1, sok, x0, Ip,P0,P1,P2, Q0,Q1,Q2, c8,c6A,c6B);
        rowStep<5>(S, r0+5, Yb, t, xc2, ok0, ok1, sok, x0, Ip,P0,P1,P2, Q0,Q1,Q2, c8,c6A,c6B);
        rowStep<6>(S, r0+6, Yb, t, xc2, ok0, ok1, sok, x0, Ip,P0,P1,P2, Q0,Q1,Q2, c8,c6A,c6B);
        rowStep<7>(S, r0+7, Yb, t, xc2, ok0, ok1, sok, x0, Ip,P0,P1,P2, Q0,Q1,Q2, c8,c6A,c6B);
    }
    // tail rows 72..75 (72 % 8 == 0, slots line up)
    rowStep<0>(S, 72, Yb, t, xc2, ok0, ok1, sok, x0, Ip,P0,P1,P2, Q0,Q1,Q2, c8,c6A,c6B);
    rowStep<1>(S, 73, Yb, t, xc2, ok0, ok1, sok, x0, Ip,P0,P1,P2, Q0,Q1,Q2, c8,c6A,c6B);
    rowStep<2>(S, 74, Yb, t, xc2, ok0, ok1, sok, x0, Ip,P0,P1,P2, Q0,Q1,Q2, c8,c6A,c6B);
    rowStep<3>(S, 75, Yb, t, xc2, ok0, ok1, sok, x0, Ip,P0,P1,P2, Q0,Q1,Q2, c8,c6A,c6B);
}

extern "C" void kernel_launch(void* const* d_in, const int* in_sizes, int n_in,
                              void* d_out, int out_size, void* d_ws, size_t ws_size,
                              hipStream_t stream) {
    const float* I = (const float*)d_in[0];
    const float* P = (const float*)d_in[1];
    // d_in[2] = radius (always 3; hardcoded)
    float* Q = (float*)d_out;

    dim3 grid(9, 16, 8);   // x-stripes (9x116=1044>=1024), y-segments, batch
    gf_kernel<<<grid, TPB, 0, stream>>>(I, P, Q);
}

// Round 6
// 309.112 us; speedup vs baseline: 1.0461x; 1.0461x over previous
//
#include <hip/hip_runtime.h>

// Guided filter r=3 (7x7 box, zero-pad /49), fused streaming kernel. R12
// (= R11 resubmitted verbatim; R11's bench died to a container-acquisition
// failure, no counters produced. Correctness re-audited: ring-slot algebra,
// clamped+aligned v2 accesses, uniform-y branches, tail gates — no fault
// path.)
//
// Cross-round invariant (R8/R9/R10): per-wave serial row time ~5k cycles
// regardless of structure; throughput scales with waves/CU only.
// R10 (C=2 parity-split, 420 LDS cyc/row, conflicts=0) dropped to 4.5
// waves/CU and regressed. R11/R12 keeps R10's cheap rows and restores
// occupancy: SEGH=32 -> 2304 blocks = 9 blocks/CU (LDS 15.2KB x9 = 137KB).
// Chain trims: register ring for I (16 VGPR) supplies Io and leaving-I,
// removing 2 of 3 per-row reload wait groups; leaving p0..p2 still
// reloaded from global (full raw ring would be ~230 VGPR = spill risk).
//
// Thread = 2 adjacent image columns (parity-split LDS: thread t writes
// even/odd arrays at idx t+2, reads even t+1..t+4, odd t..t+3 -> every
// ds op lane-dense). Block = 64 threads = 128 input cols (116 output).
// Block sweeps 44 rows (r=0..43) of a 32-row segment: entering row
// y=Yb+r, ab row yc=y-3, output row o=y-6 (valid r=12..43).
// Vertical box sums: rolling register colsums; leaving ab from depth-8
// register ring (slot=r&7, static); leaving raw p from global reload
// (1-row lead, L2), leaving/output I from the I-ring.
// LDS = 15,232 B. Grid 9x32x8 = 2304 blocks (9/CU).

typedef float v4 __attribute__((ext_vector_type(4)));
typedef float v2 __attribute__((ext_vector_type(2)));

#define TPB   64
#define OUTW  116
#define SEGH  32
#define HW    1024
#define NIDX  68           // 64 data + guards per parity array
#define EPSF  1e-6f
#define INV49 (1.0f/49.0f)

struct St {
    v4 s14[2], s58[2];         // stage-1 colsums per col
    v4 t64[2]; v2 t62[2];      // stage-2 colsums per col
    v4 rab4[8][2]; v2 rab2[8][2]; // ab ring, slot = r&7 (static via unroll)
    v2 rI[8];                  // I ring (x=col0,y=col1), slot = r&7
    v4 ent[2][2];              // entering raw rows, ping-pong [r&1][col]
    v2 lvp[3], lvpN[3];        // leaving p0,p1,p2 (reloaded, 1-row lead)
};

template<int U>
__device__ __forceinline__ void rowStep(
    St& S, const int r, const int Yb, const int t, const int xc2,
    const bool ok0, const bool ok1, const bool sok, const int x0,
    const float* __restrict__ Ip, const float* __restrict__ P0,
    const float* __restrict__ P1, const float* __restrict__ P2,
    float* __restrict__ Q0, float* __restrict__ Q1, float* __restrict__ Q2,
    v4 (* __restrict__ c8)[2][2][NIDX],
    v4 (* __restrict__ c6A)[2][NIDX],
    v2 (* __restrict__ c6B)[2][NIDX])
{
    constexpr int SU  = U & 1;        // LDS slot
    constexpr int WS  = U;            // ring write slot (r&7 == U)
    constexpr int LS  = (U + 1) & 7;  // ring leaving slot (row r-7)
    constexpr int IOS = (U + 2) & 7;  // I-ring Io slot (row r-6)

    // ---- A: stage-1 vertical colsum update (enter y, leave y-7) -> cs8
    {
        const v4 cE0 = S.ent[SU][0], cE1 = S.ent[SU][1];
        const v2 LI  = S.rI[LS];
        {   // col 0
            const float Lx = LI.x;
            const float L0 = S.lvp[0].x, L1 = S.lvp[1].x, L2 = S.lvp[2].x;
            v4 d14, d58;
            d14.x = cE0.x - Lx;
            d14.y = cE0.x*cE0.x - Lx*Lx;
            d14.z = cE0.y - L0;
            d14.w = cE0.z - L1;
            d58.x = cE0.w - L2;
            d58.y = cE0.x*cE0.y - Lx*L0;
            d58.z = cE0.x*cE0.z - Lx*L1;
            d58.w = cE0.x*cE0.w - Lx*L2;
            S.s14[0] += d14; S.s58[0] += d58;
            c8[SU][0][0][t+2] = S.s14[0];
            c8[SU][0][1][t+2] = S.s58[0];
        }
        {   // col 1
            const float Lx = LI.y;
            const float L0 = S.lvp[0].y, L1 = S.lvp[1].y, L2 = S.lvp[2].y;
            v4 d14, d58;
            d14.x = cE1.x - Lx;
            d14.y = cE1.x*cE1.x - Lx*Lx;
            d14.z = cE1.y - L0;
            d14.w = cE1.z - L1;
            d58.x = cE1.w - L2;
            d58.y = cE1.x*cE1.y - Lx*L0;
            d58.z = cE1.x*cE1.z - Lx*L1;
            d58.w = cE1.x*cE1.w - Lx*L2;
            S.s14[1] += d14; S.s58[1] += d58;
            c8[SU][1][0][t+2] = S.s14[1];
            c8[SU][1][1][t+2] = S.s58[1];
        }
        v2 nI; nI.x = cE0.x; nI.y = cE1.x;
        S.rI[WS] = nI;                      // ring holds entering I
    }
    asm volatile("" ::: "memory");

    // ---- B: stage-1 horizontal 7-tap (parity-split sliding) -> ab ->
    //         ab-ring / stage-2 colsum update -> cs6
    {
        const v4 e14_1 = c8[SU][0][0][t+1], e14_2 = c8[SU][0][0][t+2],
                 e14_3 = c8[SU][0][0][t+3], e14_4 = c8[SU][0][0][t+4];
        const v4 o14_0 = c8[SU][1][0][t+0], o14_1 = c8[SU][1][0][t+1],
                 o14_2 = c8[SU][1][0][t+2], o14_3 = c8[SU][1][0][t+3];
        const v4 w14 = (e14_1 + e14_2 + e14_3) + (o14_1 + o14_2 + o14_3);
        v4 W14[2]; W14[0] = w14 + o14_0; W14[1] = w14 + e14_4;

        const v4 e58_1 = c8[SU][0][1][t+1], e58_2 = c8[SU][0][1][t+2],
                 e58_3 = c8[SU][0][1][t+3], e58_4 = c8[SU][0][1][t+4];
        const v4 o58_0 = c8[SU][1][1][t+0], o58_1 = c8[SU][1][1][t+1],
                 o58_2 = c8[SU][1][1][t+2], o58_3 = c8[SU][1][1][t+3];
        const v4 w58 = (e58_1 + e58_2 + e58_3) + (o58_1 + o58_2 + o58_3);
        v4 W58[2]; W58[0] = w58 + o58_0; W58[1] = w58 + e58_4;

        const int  yc   = Yb + r - 3;
        const bool ycok = (unsigned)yc < HW;
        const bool okc[2] = {ok0, ok1};
        #pragma unroll
        for (int c = 0; c < 2; ++c) {
            const v4 A = W14[c], B = W58[c];
            const float mi  = A.x * INV49;
            const float mii = A.y * INV49;
            const float rv  = __builtin_amdgcn_rcpf(mii - mi*mi + EPSF);
            const bool abok = ycok && okc[c];
            const float mp0 = A.z*INV49, mp1 = A.w*INV49, mp2 = B.x*INV49;
            const float a0 = (B.y*INV49 - mi*mp0)*rv;
            const float a1 = (B.z*INV49 - mi*mp1)*rv;
            const float a2 = (B.w*INV49 - mi*mp2)*rv;
            const float b0 = fmaf(-a0, mi, mp0);
            const float b1 = fmaf(-a1, mi, mp1);
            const float b2 = fmaf(-a2, mi, mp2);
            v4 ab4; ab4.x = abok?a0:0.f; ab4.y = abok?b0:0.f;
                    ab4.z = abok?a1:0.f; ab4.w = abok?b1:0.f;
            v2 ab2; ab2.x = abok?a2:0.f; ab2.y = abok?b2:0.f;
            S.t64[c] += ab4 - S.rab4[LS][c];  S.rab4[WS][c] = ab4;
            S.t62[c] += ab2 - S.rab2[LS][c];  S.rab2[WS][c] = ab2;
            c6A[SU][c][t+2] = S.t64[c];
            c6B[SU][c][t+2] = S.t62[c];
        }
    }
    asm volatile("" ::: "memory");

    // ---- C: prefetch. Entering row r+2 from HBM (2-row lead); leaving
    //         p0..p2 for row r+1 from L2 (1-row lead). Uniform-y branches.
    {
        const int yE = Yb + r + 2;
        if (r <= 41 && (unsigned)yE < HW) {
            const size_t ro = (size_t)yE * HW + xc2;
            const v2 vI = *(const v2*)(Ip + ro);
            const v2 va = *(const v2*)(P0 + ro);
            const v2 vb = *(const v2*)(P1 + ro);
            const v2 vc = *(const v2*)(P2 + ro);
            v4 E0, E1;
            E0.x = ok0?vI.x:0.f; E0.y = ok0?va.x:0.f; E0.z = ok0?vb.x:0.f; E0.w = ok0?vc.x:0.f;
            E1.x = ok1?vI.y:0.f; E1.y = ok1?va.y:0.f; E1.z = ok1?vb.y:0.f; E1.w = ok1?vc.y:0.f;
            S.ent[SU][0] = E0; S.ent[SU][1] = E1;
        } else {
            const v4 z = {0.f,0.f,0.f,0.f};
            S.ent[SU][0] = z; S.ent[SU][1] = z;
        }
        const int yL = Yb + r - 6;         // leaving row for row r+1
        if (r >= 6 && r <= 42 && (unsigned)yL < HW) {
            const size_t ro = (size_t)yL * HW + xc2;
            const v2 va = *(const v2*)(P0 + ro);
            const v2 vb = *(const v2*)(P1 + ro);
            const v2 vc = *(const v2*)(P2 + ro);
            v2 L0, L1v, L2v;
            L0.x  = ok0?va.x:0.f; L0.y  = ok1?va.y:0.f;
            L1v.x = ok0?vb.x:0.f; L1v.y = ok1?vb.y:0.f;
            L2v.x = ok0?vc.x:0.f; L2v.y = ok1?vc.y:0.f;
            S.lvpN[0] = L0; S.lvpN[1] = L1v; S.lvpN[2] = L2v;
        } else {
            const v2 z = {0.f,0.f};
            S.lvpN[0] = z; S.lvpN[1] = z; S.lvpN[2] = z;
        }
    }

    // ---- D: stage-2 horizontal 7-tap -> output row o = y-6
    if ((unsigned)(r - 12) <= 31u) {
        const v4 eA1 = c6A[SU][0][t+1], eA2 = c6A[SU][0][t+2],
                 eA3 = c6A[SU][0][t+3], eA4 = c6A[SU][0][t+4];
        const v4 oA0 = c6A[SU][1][t+0], oA1 = c6A[SU][1][t+1],
                 oA2 = c6A[SU][1][t+2], oA3 = c6A[SU][1][t+3];
        const v2 eB1 = c6B[SU][0][t+1], eB2 = c6B[SU][0][t+2],
                 eB3 = c6B[SU][0][t+3], eB4 = c6B[SU][0][t+4];
        const v2 oB0 = c6B[SU][1][t+0], oB1 = c6B[SU][1][t+1],
                 oB2 = c6B[SU][1][t+2], oB3 = c6B[SU][1][t+3];
        const v4 wA = (eA1+eA2+eA3) + (oA1+oA2+oA3);
        const v2 wB = (eB1+eB2+eB3) + (oB1+oB2+oB3);
        const v4 A0 = wA + oA0, A1 = wA + eA4;
        const v2 B0 = wB + oB0, B1 = wB + eB4;
        if (sok) {
            const v2 io = S.rI[IOS];       // I at output row (ring, row r-6)
            const int o = Yb + r - 6;
            const size_t ob = (size_t)o * HW + x0;
            v2 q;
            q.x = fminf(fmaxf(fmaf(A0.x*INV49, io.x, A0.y*INV49), 0.f), 1.f);
            q.y = fminf(fmaxf(fmaf(A1.x*INV49, io.y, A1.y*INV49), 0.f), 1.f);
            *(v2*)(Q0 + ob) = q;
            q.x = fminf(fmaxf(fmaf(A0.z*INV49, io.x, A0.w*INV49), 0.f), 1.f);
            q.y = fminf(fmaxf(fmaf(A1.z*INV49, io.y, A1.w*INV49), 0.f), 1.f);
            *(v2*)(Q1 + ob) = q;
            q.x = fminf(fmaxf(fmaf(B0.x*INV49, io.x, B0.y*INV49), 0.f), 1.f);
            q.y = fminf(fmaxf(fmaf(B1.x*INV49, io.y, B1.y*INV49), 0.f), 1.f);
            *(v2*)(Q2 + ob) = q;
        }
    }
    S.lvp[0] = S.lvpN[0]; S.lvp[1] = S.lvpN[1]; S.lvp[2] = S.lvpN[2];
}

__global__ __launch_bounds__(TPB, 2) void gf_kernel(
    const float* __restrict__ I, const float* __restrict__ P,
    float* __restrict__ Q)
{
    // parity-split colsum rows: [slot][parity][part][idx]
    __shared__ v4 c8[2][2][2][NIDX];   // 8704 B (stage-1)
    __shared__ v4 c6A[2][2][NIDX];     // 4352 B (stage-2 a0,b0,a1,b1)
    __shared__ v2 c6B[2][2][NIDX];     // 2176 B (stage-2 a2,b2) -> 15232 B

    const int s   = blockIdx.x;      // x-stripe (9)
    const int seg = blockIdx.y;      // y-segment (32)
    const int b   = blockIdx.z;      // batch (8)
    const int t   = threadIdx.x;

    const int Yb = seg*SEGH - 6;
    const int x0 = s*OUTW - 6 + 2*t;           // even always
    const int x1 = x0 + 1;
    const bool ok0 = (unsigned)x0 < HW;
    const bool ok1 = (unsigned)x1 < HW;
    const int  xc2 = min(max(x0, 0), HW-2);    // valid base for v2 loads
    const bool sok = (t >= 3) && (t <= 60) && ok0 && ok1;

    const float* Ip = I + (size_t)b*HW*HW;
    const float* P0 = P + ((size_t)b*3 + 0)*HW*HW;
    const float* P1 = P + ((size_t)b*3 + 1)*HW*HW;
    const float* P2 = P + ((size_t)b*3 + 2)*HW*HW;
    float* Q0 = Q + ((size_t)b*3 + 0)*HW*HW;
    float* Q1 = Q + ((size_t)b*3 + 1)*HW*HW;
    float* Q2 = Q + ((size_t)b*3 + 2)*HW*HW;

    // zero-init LDS (guard cells must read as 0; interiors rewritten)
    {
        const v4 z4 = {0.f,0.f,0.f,0.f};
        const v2 z2 = {0.f,0.f};
        v4* a = (v4*)c8;
        for (int i = t; i < 2*2*2*NIDX; i += TPB) a[i] = z4;
        v4* bb = (v4*)c6A;
        for (int i = t; i < 2*2*NIDX; i += TPB) bb[i] = z4;
        v2* cc = (v2*)c6B;
        for (int i = t; i < 2*2*NIDX; i += TPB) cc[i] = z2;
    }

    St S;
    {
        const v4 z4 = {0.f,0.f,0.f,0.f};
        const v2 z2 = {0.f,0.f};
        #pragma unroll
        for (int c = 0; c < 2; ++c) {
            S.s14[c] = z4; S.s58[c] = z4; S.t64[c] = z4; S.t62[c] = z2;
            #pragma unroll
            for (int i = 0; i < 8; ++i) { S.rab4[i][c] = z4; S.rab2[i][c] = z2; }
        }
        #pragma unroll
        for (int i = 0; i < 8; ++i) S.rI[i] = z2;
        S.lvp[0] = z2; S.lvp[1] = z2; S.lvp[2] = z2;
        S.lvpN[0] = z2; S.lvpN[1] = z2; S.lvpN[2] = z2;
        // prologue: entering rows 0,1
        #pragma unroll
        for (int pr = 0; pr < 2; ++pr) {
            const int yE = Yb + pr;
            if ((unsigned)yE < HW) {
                const size_t ro = (size_t)yE * HW + xc2;
                const v2 vI = *(const v2*)(Ip + ro);
                const v2 va = *(const v2*)(P0 + ro);
                const v2 vb = *(const v2*)(P1 + ro);
                const v2 vc = *(const v2*)(P2 + ro);
                v4 E0, E1;
                E0.x = ok0?vI.x:0.f; E0.y = ok0?va.x:0.f; E0.z = ok0?vb.x:0.f; E0.w = ok0?vc.x:0.f;
                E1.x = ok1?vI.y:0.f; E1.y = ok1?va.y:0.f; E1.z = ok1?vb.y:0.f; E1.w = ok1?vc.y:0.f;
                S.ent[pr][0] = E0; S.ent[pr][1] = E1;
            } else {
                S.ent[pr][0] = z4; S.ent[pr][1] = z4;
            }
        }
    }
    __syncthreads();   // LDS zero-init visible (single wave: cheap)

    // 44 rows: r = 0..43 (ring slot r&7 == U by construction)
    for (int m = 0; m < 5; ++m) {
        const int r0 = m*8;
        rowStep<0>(S, r0+0, Yb, t, xc2, ok0, ok1, sok, x0, Ip,P0,P1,P2, Q0,Q1,Q2, c8,c6A,c6B);
        rowStep<1>(S, r0+1, Yb, t, xc2, ok0, ok1, sok, x0, Ip,P0,P1,P2, Q0,Q1,Q2, c8,c6A,c6B);
        rowStep<2>(S, r0+2, Yb, t, xc2, ok0, ok1, sok, x0, Ip,P0,P1,P2, Q0,Q1,Q2, c8,c6A,c6B);
        rowStep<3>(S, r0+3, Yb, t, xc2, ok0, ok1, sok, x0, Ip,P0,P1,P2, Q0,Q1,Q2, c8,c6A,c6B);
        rowStep<4>(S, r0+4, Yb, t, xc2, ok0, ok1, sok, x0, Ip,P0,P1,P2, Q0,Q1,Q2, c8,c6A,c6B);
        rowStep<5>(S, r0+5, Yb, t, xc2, ok0, ok1, sok, x0, Ip,P0,P1,P2, Q0,Q1,Q2, c8,c6A,c6B);
        rowStep<6>(S, r0+6, Yb, t, xc2, ok0, ok1, sok, x0, Ip,P0,P1,P2, Q0,Q1,Q2, c8,c6A,c6B);
        rowStep<7>(S, r0+7, Yb, t, xc2, ok0, ok1, sok, x0, Ip,P0,P1,P2, Q0,Q1,Q2, c8,c6A,c6B);
    }
    // tail rows 40..43 (40 % 8 == 0, slots line up)
    rowStep<0>(S, 40, Yb, t, xc2, ok0, ok1, sok, x0, Ip,P0,P1,P2, Q0,Q1,Q2, c8,c6A,c6B);
    rowStep<1>(S, 41, Yb, t, xc2, ok0, ok1, sok, x0, Ip,P0,P1,P2, Q0,Q1,Q2, c8,c6A,c6B);
    rowStep<2>(S, 42, Yb, t, xc2, ok0, ok1, sok, x0, Ip,P0,P1,P2, Q0,Q1,Q2, c8,c6A,c6B);
    rowStep<3>(S, 43, Yb, t, xc2, ok0, ok1, sok, x0, Ip,P0,P1,P2, Q0,Q1,Q2, c8,c6A,c6B);
}

extern "C" void kernel_launch(void* const* d_in, const int* in_sizes, int n_in,
                              void* d_out, int out_size, void* d_ws, size_t ws_size,
                              hipStream_t stream) {
    const float* I = (const float*)d_in[0];
    const float* P = (const float*)d_in[1];
    // d_in[2] = radius (always 3; hardcoded)
    float* Q = (float*)d_out;

    dim3 grid(9, 32, 8);   // x-stripes (9x116=1044>=1024), y-segments, batch
    gf_kernel<<<grid, TPB, 0, stream>>>(I, P, Q);
}

// Round 7
// 295.014 us; speedup vs baseline: 1.0961x; 1.0478x over previous
//
#include <hip/hip_runtime.h>

// Guided filter r=3 (7x7 box, zero-pad /49), fused streaming kernel. R13.
// Invariant found R8-R12: ~35 SIMD-cyc per output column across ALL
// structures; no pipe saturated; ~4.5 waves/CU resident regardless of
// theoretical max. => latency-bound on the per-row serial chain.
// R13 attacks the chain: (1) 2-ROW BATCHES -- phases A/B/D process two
// independent rows back-to-back, amortizing LDS first-access latency,
// phase transitions and vmcnt waits (R8's 4-row batching was the best
// kernel so far; this adds it to the cheaper C=2 parity structure).
// Single-buffer LDS (same-wave in-order DS, already relied on in
// R10/R12) keeps LDS at 15232B. (2) next-batch global loads issued
// between phase A and B (T14 async-stage: latency hides under 2 rows of
// tap math). (3) template<bool INT> interior specialization: 73% of
// blocks skip all clamps/zero-selects (~60-80 VALU/row).
//
// Thread = 2 adjacent image columns (parity-split LDS: thread t writes
// even/odd arrays at idx t+2, reads even t+1..t+4, odd t..t+3 -> every
// ds op lane-dense). Block = 64 threads = 128 input cols (116 output).
// Block sweeps 44 rows (r=0..43) of a 32-row segment as 22 two-row
// batches: entering row y=Yb+r, ab row yc=y-3, output row o=y-6
// (valid r=12..43). Vertical sums: rolling register colsums; leaving ab
// from depth-8 register ring (slot=r&7, static); leaving p0..p2 from
// global reload (1-batch lead, L2); leaving/output I from I-ring.
// LDS = 15,232 B. Grid 9x32x8 = 2304 blocks (9/CU).

typedef float v4 __attribute__((ext_vector_type(4)));
typedef float v2 __attribute__((ext_vector_type(2)));

#define TPB   64
#define OUTW  116
#define SEGH  32
#define HW    1024
#define NIDX  68           // 64 data + guards per parity array
#define EPSF  1e-6f
#define INV49 (1.0f/49.0f)

struct St {
    v4 s14[2], s58[2];            // stage-1 colsums per col
    v4 t64[2]; v2 t62[2];         // stage-2 colsums per col
    v4 rab4[8][2]; v2 rab2[8][2]; // ab ring, slot = r&7 (static idx)
    v2 rI[8];                     // I ring (x=col0,y=col1), slot = r&7
    v4 ent[2][2];                 // entering rows this batch [q][col]
    v2 lvp[2][3], lvpN[2][3];     // leaving p0..p2 [q][ch], 1-batch lead
};

struct Ctx {
    const float *Ip, *P0, *P1, *P2;
    float *Q0, *Q1, *Q2;
    int t, x0, xc2, Yb;
    bool ok0, ok1, sok;
};

// ---- phase A (one row): vertical colsum update -> cs8 LDS
template<int RS, int Q, bool INT>
__device__ __forceinline__ void phA(St& S, const Ctx& C,
    v4 (* __restrict__ c8)[2][2][NIDX])
{
    constexpr int WS = RS & 7, LS = (RS+1)&7;
    const v4 cE0 = S.ent[Q][0], cE1 = S.ent[Q][1];
    const v2 LI  = S.rI[LS];
    {   // col 0
        const float Lx = LI.x;
        const float L0 = S.lvp[Q][0].x, L1 = S.lvp[Q][1].x, L2 = S.lvp[Q][2].x;
        v4 d14, d58;
        d14.x = cE0.x - Lx;
        d14.y = cE0.x*cE0.x - Lx*Lx;
        d14.z = cE0.y - L0;
        d14.w = cE0.z - L1;
        d58.x = cE0.w - L2;
        d58.y = cE0.x*cE0.y - Lx*L0;
        d58.z = cE0.x*cE0.z - Lx*L1;
        d58.w = cE0.x*cE0.w - Lx*L2;
        S.s14[0] += d14; S.s58[0] += d58;
        c8[Q][0][0][C.t+2] = S.s14[0];
        c8[Q][0][1][C.t+2] = S.s58[0];
    }
    {   // col 1
        const float Lx = LI.y;
        const float L0 = S.lvp[Q][0].y, L1 = S.lvp[Q][1].y, L2 = S.lvp[Q][2].y;
        v4 d14, d58;
        d14.x = cE1.x - Lx;
        d14.y = cE1.x*cE1.x - Lx*Lx;
        d14.z = cE1.y - L0;
        d14.w = cE1.z - L1;
        d58.x = cE1.w - L2;
        d58.y = cE1.x*cE1.y - Lx*L0;
        d58.z = cE1.x*cE1.z - Lx*L1;
        d58.w = cE1.x*cE1.w - Lx*L2;
        S.s14[1] += d14; S.s58[1] += d58;
        c8[Q][1][0][C.t+2] = S.s14[1];
        c8[Q][1][1][C.t+2] = S.s58[1];
    }
    v2 nI; nI.x = cE0.x; nI.y = cE1.x;
    S.rI[WS] = nI;                      // ring holds entering I
}

// ---- phase B (one row): stage-1 horizontal 7-tap -> ab -> ring ->
//      stage-2 colsums -> cs6 LDS
template<int RS, int Q, bool INT>
__device__ __forceinline__ void phB(St& S, const Ctx& C, const int yc,
    v4 (* __restrict__ c8)[2][2][NIDX], v4 (* __restrict__ c6A)[2][NIDX],
    v2 (* __restrict__ c6B)[2][NIDX])
{
    constexpr int WS = RS & 7, LS = (RS+1)&7;
    const int t = C.t;
    const v4 e14_1 = c8[Q][0][0][t+1], e14_2 = c8[Q][0][0][t+2],
             e14_3 = c8[Q][0][0][t+3], e14_4 = c8[Q][0][0][t+4];
    const v4 o14_0 = c8[Q][1][0][t+0], o14_1 = c8[Q][1][0][t+1],
             o14_2 = c8[Q][1][0][t+2], o14_3 = c8[Q][1][0][t+3];
    const v4 w14 = (e14_1 + e14_2 + e14_3) + (o14_1 + o14_2 + o14_3);
    v4 W14[2]; W14[0] = w14 + o14_0; W14[1] = w14 + e14_4;

    const v4 e58_1 = c8[Q][0][1][t+1], e58_2 = c8[Q][0][1][t+2],
             e58_3 = c8[Q][0][1][t+3], e58_4 = c8[Q][0][1][t+4];
    const v4 o58_0 = c8[Q][1][1][t+0], o58_1 = c8[Q][1][1][t+1],
             o58_2 = c8[Q][1][1][t+2], o58_3 = c8[Q][1][1][t+3];
    const v4 w58 = (e58_1 + e58_2 + e58_3) + (o58_1 + o58_2 + o58_3);
    v4 W58[2]; W58[0] = w58 + o58_0; W58[1] = w58 + e58_4;

    const bool ycok = INT ? true : ((unsigned)yc < HW);
    const bool okc[2] = {C.ok0, C.ok1};
    #pragma unroll
    for (int c = 0; c < 2; ++c) {
        const v4 A = W14[c], B = W58[c];
        const float mi  = A.x * INV49;
        const float mii = A.y * INV49;
        const float rv  = __builtin_amdgcn_rcpf(mii - mi*mi + EPSF);
        const float mp0 = A.z*INV49, mp1 = A.w*INV49, mp2 = B.x*INV49;
        const float a0 = (B.y*INV49 - mi*mp0)*rv;
        const float a1 = (B.z*INV49 - mi*mp1)*rv;
        const float a2 = (B.w*INV49 - mi*mp2)*rv;
        const float b0 = fmaf(-a0, mi, mp0);
        const float b1 = fmaf(-a1, mi, mp1);
        const float b2 = fmaf(-a2, mi, mp2);
        v4 ab4; v2 ab2;
        if constexpr (INT) {
            ab4.x = a0; ab4.y = b0; ab4.z = a1; ab4.w = b1;
            ab2.x = a2; ab2.y = b2;
        } else {
            const bool abok = ycok && okc[c];
            ab4.x = abok?a0:0.f; ab4.y = abok?b0:0.f;
            ab4.z = abok?a1:0.f; ab4.w = abok?b1:0.f;
            ab2.x = abok?a2:0.f; ab2.y = abok?b2:0.f;
        }
        S.t64[c] += ab4 - S.rab4[LS][c];  S.rab4[WS][c] = ab4;
        S.t62[c] += ab2 - S.rab2[LS][c];  S.rab2[WS][c] = ab2;
        c6A[Q][c][t+2] = S.t64[c];
        c6B[Q][c][t+2] = S.t62[c];
    }
}

// ---- phase D (one row): stage-2 horizontal 7-tap -> output
template<int RS, int Q, bool INT>
__device__ __forceinline__ void phD(St& S, const Ctx& C, const int o,
    v4 (* __restrict__ c6A)[2][NIDX], v2 (* __restrict__ c6B)[2][NIDX])
{
    constexpr int IOS = (RS+2)&7;
    const int t = C.t;
    const v4 eA1 = c6A[Q][0][t+1], eA2 = c6A[Q][0][t+2],
             eA3 = c6A[Q][0][t+3], eA4 = c6A[Q][0][t+4];
    const v4 oA0 = c6A[Q][1][t+0], oA1 = c6A[Q][1][t+1],
             oA2 = c6A[Q][1][t+2], oA3 = c6A[Q][1][t+3];
    const v2 eB1 = c6B[Q][0][t+1], eB2 = c6B[Q][0][t+2],
             eB3 = c6B[Q][0][t+3], eB4 = c6B[Q][0][t+4];
    const v2 oB0 = c6B[Q][1][t+0], oB1 = c6B[Q][1][t+1],
             oB2 = c6B[Q][1][t+2], oB3 = c6B[Q][1][t+3];
    const v4 wA = (eA1+eA2+eA3) + (oA1+oA2+oA3);
    const v2 wB = (eB1+eB2+eB3) + (oB1+oB2+oB3);
    const v4 A0 = wA + oA0, A1 = wA + eA4;
    const v2 B0 = wB + oB0, B1 = wB + eB4;
    if (C.sok) {
        const v2 io = S.rI[IOS];       // I at output row (ring, row RS-6)
        const size_t ob = (size_t)o * HW + C.x0;
        v2 q;
        q.x = fminf(fmaxf(fmaf(A0.x*INV49, io.x, A0.y*INV49), 0.f), 1.f);
        q.y = fminf(fmaxf(fmaf(A1.x*INV49, io.y, A1.y*INV49), 0.f), 1.f);
        *(v2*)(C.Q0 + ob) = q;
        q.x = fminf(fmaxf(fmaf(A0.z*INV49, io.x, A0.w*INV49), 0.f), 1.f);
        q.y = fminf(fmaxf(fmaf(A1.z*INV49, io.y, A1.w*INV49), 0.f), 1.f);
        *(v2*)(C.Q1 + ob) = q;
        q.x = fminf(fmaxf(fmaf(B0.x*INV49, io.x, B0.y*INV49), 0.f), 1.f);
        q.y = fminf(fmaxf(fmaf(B1.x*INV49, io.y, B1.y*INV49), 0.f), 1.f);
        *(v2*)(C.Q2 + ob) = q;
    }
}

// ---- one 2-row batch: rows rb (q=0), rb+1 (q=1); U = rb&7 (0,2,4,6)
template<int U, bool INT>
__device__ __forceinline__ void batchStep(St& S, const Ctx& C, const int rb,
    v4 (* __restrict__ c8)[2][2][NIDX], v4 (* __restrict__ c6A)[2][NIDX],
    v2 (* __restrict__ c6B)[2][NIDX])
{
    phA<U,   0, INT>(S, C, c8);
    phA<U+1, 1, INT>(S, C, c8);

    // issue next-batch loads EARLY (consumed next batch; latency hides
    // under this batch's taps). rows rb+2, rb+3 exist iff rb <= 40.
    if (rb <= 40) {
        #pragma unroll
        for (int q = 0; q < 2; ++q) {
            const int yE = C.Yb + rb + 2 + q;
            if (INT || (unsigned)yE < HW) {
                const size_t ro = (size_t)yE*HW + (size_t)(INT ? C.x0 : C.xc2);
                const v2 vI = *(const v2*)(C.Ip + ro);
                const v2 va = *(const v2*)(C.P0 + ro);
                const v2 vb = *(const v2*)(C.P1 + ro);
                const v2 vc = *(const v2*)(C.P2 + ro);
                v4 E0, E1;
                if constexpr (INT) {
                    E0.x=vI.x; E0.y=va.x; E0.z=vb.x; E0.w=vc.x;
                    E1.x=vI.y; E1.y=va.y; E1.z=vb.y; E1.w=vc.y;
                } else {
                    E0.x=C.ok0?vI.x:0.f; E0.y=C.ok0?va.x:0.f;
                    E0.z=C.ok0?vb.x:0.f; E0.w=C.ok0?vc.x:0.f;
                    E1.x=C.ok1?vI.y:0.f; E1.y=C.ok1?va.y:0.f;
                    E1.z=C.ok1?vb.y:0.f; E1.w=C.ok1?vc.y:0.f;
                }
                S.ent[q][0] = E0; S.ent[q][1] = E1;
            } else {
                const v4 z = {0.f,0.f,0.f,0.f};
                S.ent[q][0] = z; S.ent[q][1] = z;
            }
        }
        #pragma unroll
        for (int q = 0; q < 2; ++q) {
            const int R2 = rb + 2 + q;         // next-batch row
            const int yL = C.Yb + R2 - 7;      // its leaving image row
            if (R2 >= 7 && (INT || (unsigned)yL < HW)) {
                const size_t ro = (size_t)yL*HW + (size_t)(INT ? C.x0 : C.xc2);
                const v2 va = *(const v2*)(C.P0 + ro);
                const v2 vb = *(const v2*)(C.P1 + ro);
                const v2 vc = *(const v2*)(C.P2 + ro);
                if constexpr (INT) {
                    S.lvpN[q][0] = va; S.lvpN[q][1] = vb; S.lvpN[q][2] = vc;
                } else {
                    v2 L0, L1, L2;
                    L0.x = C.ok0?va.x:0.f; L0.y = C.ok1?va.y:0.f;
                    L1.x = C.ok0?vb.x:0.f; L1.y = C.ok1?vb.y:0.f;
                    L2.x = C.ok0?vc.x:0.f; L2.y = C.ok1?vc.y:0.f;
                    S.lvpN[q][0] = L0; S.lvpN[q][1] = L1; S.lvpN[q][2] = L2;
                }
            } else {
                const v2 z = {0.f,0.f};
                S.lvpN[q][0] = z; S.lvpN[q][1] = z; S.lvpN[q][2] = z;
            }
        }
    }
    asm volatile("" ::: "memory");

    phB<U,   0, INT>(S, C, C.Yb + rb - 3, c8, c6A, c6B);
    phB<U+1, 1, INT>(S, C, C.Yb + rb - 2, c8, c6A, c6B);

    if (rb >= 12) {     // outputs start at batch rb=12 (both rows valid)
        phD<U,   0, INT>(S, C, C.Yb + rb - 6, c6A, c6B);
        phD<U+1, 1, INT>(S, C, C.Yb + rb - 5, c6A, c6B);
    }
    #pragma unroll
    for (int q = 0; q < 2; ++q) {
        S.lvp[q][0] = S.lvpN[q][0];
        S.lvp[q][1] = S.lvpN[q][1];
        S.lvp[q][2] = S.lvpN[q][2];
    }
}

template<bool INT>
__device__ __forceinline__ void mainLoop(St& S, const Ctx& C,
    v4 (* __restrict__ c8)[2][2][NIDX], v4 (* __restrict__ c6A)[2][NIDX],
    v2 (* __restrict__ c6B)[2][NIDX])
{
    for (int m = 0; m < 5; ++m) {      // batches rb = 8m + {0,2,4,6} (<=38)
        const int rb = m*8;
        batchStep<0, INT>(S, C, rb,   c8, c6A, c6B);
        batchStep<2, INT>(S, C, rb+2, c8, c6A, c6B);
        batchStep<4, INT>(S, C, rb+4, c8, c6A, c6B);
        batchStep<6, INT>(S, C, rb+6, c8, c6A, c6B);
    }
    batchStep<0, INT>(S, C, 40, c8, c6A, c6B);   // rows 40,41
    batchStep<2, INT>(S, C, 42, c8, c6A, c6B);   // rows 42,43
}

__global__ __launch_bounds__(TPB, 2) void gf_kernel(
    const float* __restrict__ I, const float* __restrict__ P,
    float* __restrict__ Q)
{
    // parity-split colsum rows: single-buffered, [row-in-batch q][...]
    __shared__ v4 c8[2][2][2][NIDX];   // 8704 B (stage-1: [q][par][part])
    __shared__ v4 c6A[2][2][NIDX];     // 4352 B (stage-2 a0,b0,a1,b1)
    __shared__ v2 c6B[2][2][NIDX];     // 2176 B (stage-2 a2,b2) -> 15232 B

    const int s   = blockIdx.x;      // x-stripe (9)
    const int seg = blockIdx.y;      // y-segment (32)
    const int b   = blockIdx.z;      // batch (8)
    const int t   = threadIdx.x;

    Ctx C;
    C.t  = t;
    C.Yb = seg*SEGH - 6;
    C.x0 = s*OUTW - 6 + 2*t;                   // even always
    const int x1 = C.x0 + 1;
    C.ok0 = (unsigned)C.x0 < HW;
    C.ok1 = (unsigned)x1   < HW;
    C.xc2 = min(max(C.x0, 0), HW-2);           // valid base for v2 loads
    C.sok = (t >= 3) && (t <= 60) && C.ok0 && C.ok1;
    C.Ip = I + (size_t)b*HW*HW;
    C.P0 = P + ((size_t)b*3 + 0)*HW*HW;
    C.P1 = P + ((size_t)b*3 + 1)*HW*HW;
    C.P2 = P + ((size_t)b*3 + 2)*HW*HW;
    C.Q0 = Q + ((size_t)b*3 + 0)*HW*HW;
    C.Q1 = Q + ((size_t)b*3 + 1)*HW*HW;
    C.Q2 = Q + ((size_t)b*3 + 2)*HW*HW;

    // zero-init LDS (guard cells must read as 0; interiors rewritten)
    {
        const v4 z4 = {0.f,0.f,0.f,0.f};
        const v2 z2 = {0.f,0.f};
        v4* a = (v4*)c8;
        for (int i = t; i < 2*2*2*NIDX; i += TPB) a[i] = z4;
        v4* bb = (v4*)c6A;
        for (int i = t; i < 2*2*NIDX; i += TPB) bb[i] = z4;
        v2* cc = (v2*)c6B;
        for (int i = t; i < 2*2*NIDX; i += TPB) cc[i] = z2;
    }

    St S;
    {
        const v4 z4 = {0.f,0.f,0.f,0.f};
        const v2 z2 = {0.f,0.f};
        #pragma unroll
        for (int c = 0; c < 2; ++c) {
            S.s14[c] = z4; S.s58[c] = z4; S.t64[c] = z4; S.t62[c] = z2;
            #pragma unroll
            for (int i = 0; i < 8; ++i) { S.rab4[i][c] = z4; S.rab2[i][c] = z2; }
        }
        #pragma unroll
        for (int i = 0; i < 8; ++i) S.rI[i] = z2;
        #pragma unroll
        for (int q = 0; q < 2; ++q) {
            S.lvp[q][0]=z2; S.lvp[q][1]=z2; S.lvp[q][2]=z2;
            S.lvpN[q][0]=z2; S.lvpN[q][1]=z2; S.lvpN[q][2]=z2;
        }
        // prologue: entering rows 0,1 -> ent[0], ent[1] (predicated)
        #pragma unroll
        for (int q = 0; q < 2; ++q) {
            const int yE = C.Yb + q;
            if ((unsigned)yE < HW) {
                const size_t ro = (size_t)yE * HW + C.xc2;
                const v2 vI = *(const v2*)(C.Ip + ro);
                const v2 va = *(const v2*)(C.P0 + ro);
                const v2 vb = *(const v2*)(C.P1 + ro);
                const v2 vc = *(const v2*)(C.P2 + ro);
                v4 E0, E1;
                E0.x=C.ok0?vI.x:0.f; E0.y=C.ok0?va.x:0.f;
                E0.z=C.ok0?vb.x:0.f; E0.w=C.ok0?vc.x:0.f;
                E1.x=C.ok1?vI.y:0.f; E1.y=C.ok1?va.y:0.f;
                E1.z=C.ok1?vb.y:0.f; E1.w=C.ok1?vc.y:0.f;
                S.ent[q][0] = E0; S.ent[q][1] = E1;
            } else {
                S.ent[q][0] = z4; S.ent[q][1] = z4;
            }
        }
    }
    __syncthreads();   // LDS zero-init visible (single wave: cheap)

    const bool interior = (s >= 1) && (s <= 7) && (seg >= 1) && (seg <= 30);
    if (interior) mainLoop<true >(S, C, c8, c6A, c6B);
    else          mainLoop<false>(S, C, c8, c6A, c6B);
}

extern "C" void kernel_launch(void* const* d_in, const int* in_sizes, int n_in,
                              void* d_out, int out_size, void* d_ws, size_t ws_size,
                              hipStream_t stream) {
    const float* I = (const float*)d_in[0];
    const float* P = (const float*)d_in[1];
    // d_in[2] = radius (always 3; hardcoded)
    float* Q = (float*)d_out;

    dim3 grid(9, 32, 8);   // x-stripes (9x116=1044>=1024), y-segments, batch
    gf_kernel<<<grid, TPB, 0, stream>>>(I, P, Q);
}